// Round 1
// baseline (323.614 us; speedup 1.0000x reference)
//
#include <hip/hip_runtime.h>
#include <cstdint>

#define BH 48
#define SEQ 4096
#define DIM 64
#define SEG 64
#define NCHUNK 16
#define CHUNK 256
#define PAD 68

static constexpr float INV_SCALE = 0.35355339059327379f; // 1/sqrt(sqrt(64))

// workspace float offsets
#define OFF_QL   0u         // 48*4096
#define OFF_KL   196608u    // 48*4096
#define OFF_K2   393216u    // 48*4096
#define OFF_W    589824u    // 48*4096
#define OFF_P    786432u    // 48*4096
#define OFF_MNUM 983040u    // 48*16*4096 = 3145728
#define OFF_MDEN 4128768u   // 48*16*64  = 49152
#define OFF_CMAX 4177920u   // 48
#define OFF_RMAX 4177968u   // 48   (total 4178016 floats ~ 16.7 MB)

__device__ __forceinline__ float4 ld4(const float* p){ return *reinterpret_cast<const float4*>(p); }
__device__ __forceinline__ void st4(float* p, float4 v){ *reinterpret_cast<float4*>(p) = v; }

// C[4][4] += A[i0..i0+3][:] * B[:][j0..j0+3], 64-deep, LDS operands (pad=68 keeps 16B align)
__device__ __forceinline__ void mm_tile(float c[4][4], const float (*A)[PAD], const float (*B)[PAD], int i0, int j0){
  #pragma unroll 4
  for(int k=0;k<64;k+=4){
    float4 a4[4];
    #pragma unroll
    for(int r=0;r<4;r++) a4[r] = ld4(&A[i0+r][k]);
    #pragma unroll
    for(int kk=0;kk<4;kk++){
      float4 bv = ld4(&B[k+kk][j0]);
      #pragma unroll
      for(int r=0;r<4;r++){
        float a = ((const float*)&a4[r])[kk];
        c[r][0] += a*bv.x; c[r][1] += a*bv.y; c[r][2] += a*bv.z; c[r][3] += a*bv.w;
      }
    }
  }
}

// same, but A rows come straight from global (row-major, stride 64) — L2-resident broadcast reads
__device__ __forceinline__ void mm_tile_gA(float c[4][4], const float* __restrict__ gA, const float (*B)[PAD], int i0, int j0){
  #pragma unroll 4
  for(int k=0;k<64;k+=4){
    float4 a4[4];
    #pragma unroll
    for(int r=0;r<4;r++) a4[r] = ld4(gA + (i0+r)*64 + k);
    #pragma unroll
    for(int kk=0;kk<4;kk++){
      float4 bv = ld4(&B[k+kk][j0]);
      #pragma unroll
      for(int r=0;r<4;r++){
        float a = ((const float*)&a4[r])[kk];
        c[r][0] += a*bv.x; c[r][1] += a*bv.y; c[r][2] += a*bv.z; c[r][3] += a*bv.w;
      }
    }
  }
}

// C[4][4] += A * (dg*I - B)   (Newton-Schulz steps)
__device__ __forceinline__ void mm_tile_diag(float c[4][4], const float (*A)[PAD], const float (*B)[PAD], int i0, int j0, float dg){
  #pragma unroll 4
  for(int k=0;k<64;k+=4){
    float4 a4[4];
    #pragma unroll
    for(int r=0;r<4;r++) a4[r] = ld4(&A[i0+r][k]);
    #pragma unroll
    for(int kk=0;kk<4;kk++){
      float4 bv = ld4(&B[k+kk][j0]);
      float b0=-bv.x, b1=-bv.y, b2=-bv.z, b3=-bv.w;
      int dd = k+kk-j0;
      if(dd==0) b0+=dg; else if(dd==1) b1+=dg; else if(dd==2) b2+=dg; else if(dd==3) b3+=dg;
      #pragma unroll
      for(int r=0;r<4;r++){
        float a = ((const float*)&a4[r])[kk];
        c[r][0]+=a*b0; c[r][1]+=a*b1; c[r][2]+=a*b2; c[r][3]+=a*b3;
      }
    }
  }
}

// ---------------- 1. landmark pooling (reads Q,K once; writes scaled QL,KL) ----------------
__global__ __launch_bounds__(256) void pool_kernel(const float* __restrict__ Qg, const float* __restrict__ Kg, float* __restrict__ ws){
  int bx = blockIdx.x;              // 48 heads * 2 tensors * 16 landmark-groups = 1536
  int head = bx >> 5;
  int rest = bx & 31;
  int tensor = rest >> 4;           // 0:Q 1:K
  int l0 = (rest & 15) * 4;
  int t = threadIdx.x;
  int ll = t >> 6;                  // wave id -> local landmark
  int lane = t & 63;
  int d4 = (lane & 15) * 4;
  int rq = lane >> 4;               // row phase 0..3
  const float* src = tensor ? Kg : Qg;
  float* dst = ws + (tensor ? OFF_KL : OFF_QL);
  int l = l0 + ll;
  const float* base = src + ((size_t)head*SEQ + (size_t)l*SEG)*DIM + d4;
  float sx=0.f, sy=0.f, sz=0.f, sw=0.f;
  #pragma unroll 4
  for(int r=rq; r<SEG; r+=4){
    float4 v = ld4(base + (size_t)r*DIM);
    sx+=v.x; sy+=v.y; sz+=v.z; sw+=v.w;
  }
  sx += __shfl_xor(sx,16); sy += __shfl_xor(sy,16); sz += __shfl_xor(sz,16); sw += __shfl_xor(sw,16);
  sx += __shfl_xor(sx,32); sy += __shfl_xor(sy,32); sz += __shfl_xor(sz,32); sw += __shfl_xor(sw,32);
  if(rq==0){
    const float sc = INV_SCALE / 64.0f;
    float4 o; o.x=sx*sc; o.y=sy*sc; o.z=sz*sc; o.w=sw*sc;
    st4(dst + ((size_t)head*64 + l)*DIM + d4, o);
  }
}

// ---------------- 2. kernel_2 softmax + per-head L1 row/col max ----------------
__global__ __launch_bounds__(256) void k2_kernel(float* __restrict__ ws){
  __shared__ float sQ[64][65];
  __shared__ float sK[64][65];
  __shared__ float sE[64][65];
  __shared__ float red[128];
  int h = blockIdx.x, t = threadIdx.x;
  const float* QL = ws + OFF_QL + (size_t)h*4096;
  const float* KL = ws + OFF_KL + (size_t)h*4096;
  for(int i=t;i<4096;i+=256){ sQ[i>>6][i&63]=QL[i]; sK[i>>6][i&63]=KL[i]; }
  __syncthreads();
  int i = t>>2, q = t&3;
  float l[16];
  #pragma unroll
  for(int jj=0;jj<16;jj++){
    int j = q*16+jj;
    float s=0.f;
    for(int d=0;d<64;d++) s += sQ[i][d]*sK[j][d];
    l[jj]=s;
  }
  float mx = l[0];
  #pragma unroll
  for(int jj=1;jj<16;jj++) mx = fmaxf(mx,l[jj]);
  mx = fmaxf(mx, __shfl_xor(mx,1));
  mx = fmaxf(mx, __shfl_xor(mx,2));
  float sum=0.f;
  #pragma unroll
  for(int jj=0;jj<16;jj++){ l[jj]=__expf(l[jj]-mx); sum+=l[jj]; }
  sum += __shfl_xor(sum,1);
  sum += __shfl_xor(sum,2);
  float inv = 1.0f/sum;
  #pragma unroll
  for(int jj=0;jj<16;jj++) sE[i][q*16+jj] = l[jj]*inv;
  __syncthreads();
  float* K2 = ws + OFF_K2 + (size_t)h*4096;
  for(int idx=t; idx<4096; idx+=256) K2[idx] = sE[idx>>6][idx&63];
  if(t<64){
    float cs=0.f, rs=0.f;
    for(int r=0;r<64;r++){ cs += sE[r][t]; rs += sE[t][r]; }
    red[t]=cs; red[64+t]=rs;
  }
  __syncthreads();
  if(t==0){
    float cm=0.f, rm=0.f;
    for(int j=0;j<64;j++){ cm=fmaxf(cm,red[j]); rm=fmaxf(rm,red[64+j]); }
    ws[OFF_CMAX+h]=cm; ws[OFF_RMAX+h]=rm;
  }
}

// ---------------- 3. fused: Newton-Schulz (blocks 0..47) || kernel_3@V partials (blocks 48..815) ----------------
// 3 LDS buffers (52.2 KB) -> 3 blocks/CU; chunk grid 768 = 256 CU x 3 exactly.
__global__ __launch_bounds__(256) void fused_kernel(const float* __restrict__ Kg, const float* __restrict__ Vg, float* __restrict__ ws){
  __shared__ float buf[3][64][PAD];
  __shared__ float sscale;
  int bid = blockIdx.x, t = threadIdx.x;
  int i0 = (t>>4)*4, j0 = (t&15)*4;
  if(bid < BH){
    // ---- Newton-Schulz pseudo-inverse of kernel_2, head=bid. Km stays in global (L2). ----
    int h = bid;
    float (*Vm)[PAD]=buf[0]; float (*B1)[PAD]=buf[1]; float (*B2)[PAD]=buf[2];
    const float* K2 = ws + OFF_K2 + (size_t)h*4096;
    if(t==0){
      float cm=0.f, rm=0.f;
      for(int j=0;j<BH;j++){ cm=fmaxf(cm,ws[OFF_CMAX+j]); rm=fmaxf(rm,ws[OFF_RMAX+j]); }
      sscale = 1.0f/(cm*rm);   // global (all heads) scale, matches reference
    }
    __syncthreads();
    float scale = sscale;
    for(int i=t;i<4096;i+=256) Vm[i&63][i>>6] = scale * K2[i];  // scale * Km^T (coalesced global read)
    __syncthreads();
    for(int it=0; it<6; it++){
      { // B1 = Km @ Vm   (KV), A from global
        float c[4][4]={};
        mm_tile_gA(c,K2,Vm,i0,j0);
        #pragma unroll
        for(int r=0;r<4;r++){ float4 o; o.x=c[r][0];o.y=c[r][1];o.z=c[r][2];o.w=c[r][3]; st4(&B1[i0+r][j0],o); }
        __syncthreads();
      }
      { // B2 = KV @ (7I - KV)
        float c[4][4]={};
        mm_tile_diag(c,B1,B1,i0,j0,7.0f);
        #pragma unroll
        for(int r=0;r<4;r++){ float4 o; o.x=c[r][0];o.y=c[r][1];o.z=c[r][2];o.w=c[r][3]; st4(&B2[i0+r][j0],o); }
        __syncthreads();
      }
      { // B1 = KV @ (15I - B2)   (in-place on B1: compute -> barrier -> write)
        float c[4][4]={};
        mm_tile_diag(c,B1,B2,i0,j0,15.0f);
        __syncthreads();
        #pragma unroll
        for(int r=0;r<4;r++){ float4 o; o.x=c[r][0];o.y=c[r][1];o.z=c[r][2];o.w=c[r][3]; st4(&B1[i0+r][j0],o); }
        __syncthreads();
      }
      { // Vm = 0.25 * Vm @ (13I - B1)
        float c[4][4]={};
        mm_tile_diag(c,Vm,B1,i0,j0,13.0f);
        __syncthreads();
        #pragma unroll
        for(int r=0;r<4;r++){ float4 o; o.x=0.25f*c[r][0];o.y=0.25f*c[r][1];o.z=0.25f*c[r][2];o.w=0.25f*c[r][3]; st4(&Vm[i0+r][j0],o); }
        __syncthreads();
      }
    }
    float* W = ws + OFF_W + (size_t)h*4096;
    for(int i=t;i<4096;i+=256) W[i] = Vm[i>>6][i&63];
  } else {
    // ---- kernel_3 @ V partial: block = (head, 256-key chunk); E overwrites the K-tile buffer ----
    int b = bid - BH;
    int h = b >> 4, ch = b & 15;
    float (*QLT)[PAD]=buf[0]; float (*KtE)[PAD]=buf[1]; float (*Vt)[PAD]=buf[2];
    const float* QL = ws + OFF_QL + (size_t)h*4096;
    for(int i=t;i<1024;i+=256){
      int m=i>>4, d4=(i&15)*4;
      float4 v = ld4(QL + m*64 + d4);
      QLT[d4+0][m]=v.x; QLT[d4+1][m]=v.y; QLT[d4+2][m]=v.z; QLT[d4+3][m]=v.w;   // QL^T for logits
    }
    float acc[4][4]={};
    float den=0.f;
    int mden=t>>2, qden=t&3;
    const size_t kbase = ((size_t)h*SEQ + (size_t)ch*CHUNK)*DIM;
    for(int tile=0;tile<CHUNK/64;tile++){
      __syncthreads();   // protect LDS reuse (also covers QLT on first pass)
      for(int i=t;i<1024;i+=256){
        int r=i>>4, d4=(i&15)*4;
        size_t off = kbase + (size_t)(tile*64+r)*DIM + d4;
        float4 kv = ld4(Kg+off);
        kv.x*=INV_SCALE; kv.y*=INV_SCALE; kv.z*=INV_SCALE; kv.w*=INV_SCALE;
        st4(&KtE[r][d4],kv);
        st4(&Vt[r][d4], ld4(Vg+off));
      }
      __syncthreads();
      // logits L[s'][m] = Kt(scaled) . QL
      float l[4][4]={};
      mm_tile(l, KtE, QLT, i0, j0);
      __syncthreads();   // all reads of Kt done -> overwrite with E^T
      // ET[m][s'] = exp(L[s'][m]) — register 4x4 transpose, float4 stores
      #pragma unroll
      for(int cc=0;cc<4;cc++){
        float4 o; o.x=__expf(l[0][cc]); o.y=__expf(l[1][cc]); o.z=__expf(l[2][cc]); o.w=__expf(l[3][cc]);
        st4(&KtE[j0+cc][i0], o);
      }
      __syncthreads();
      // denominator partials (softmax over full S; logits tiny so no max-sub needed)
      #pragma unroll
      for(int u=0;u<4;u++){
        float4 e2 = ld4(&KtE[mden][qden*16 + u*4]);
        den += e2.x+e2.y+e2.z+e2.w;
      }
      // acc[m][d] += ET[m][s'] * V[s'][d]
      mm_tile(acc, KtE, Vt, i0, j0);
    }
    float* num = ws + OFF_MNUM + (size_t)b*4096;
    #pragma unroll
    for(int r=0;r<4;r++){
      float4 o; o.x=acc[r][0]; o.y=acc[r][1]; o.z=acc[r][2]; o.w=acc[r][3];
      st4(num + (i0+r)*64 + j0, o);
    }
    den += __shfl_xor(den,1);
    den += __shfl_xor(den,2);
    if(qden==0) ws[OFF_MDEN + (size_t)b*64 + mden] = den;
  }
}

// ---------------- 4. combine partials -> M, then P = W @ M ----------------
__global__ __launch_bounds__(256) void combine_kernel(float* __restrict__ ws){
  __shared__ float sW[64][PAD];
  __shared__ float sM[64][PAD];
  __shared__ float sden[64];
  int h=blockIdx.x, t=threadIdx.x;
  if(t<64){
    float s=0.f;
    for(int c=0;c<NCHUNK;c++) s += ws[OFF_MDEN + ((size_t)h*NCHUNK+c)*64 + t];
    sden[t]=1.0f/s;
  }
  for(int i=t;i<4096;i+=256) sW[i>>6][i&63] = ws[OFF_W + (size_t)h*4096 + i];
  __syncthreads();
  for(int i=t;i<1024;i+=256){
    int m=i>>4, d4=(i&15)*4;
    float sx=0.f,sy=0.f,sz=0.f,sw2=0.f;
    for(int c=0;c<NCHUNK;c++){
      float4 v = ld4(ws + OFF_MNUM + ((size_t)h*NCHUNK+c)*4096 + m*64 + d4);
      sx+=v.x; sy+=v.y; sz+=v.z; sw2+=v.w;
    }
    float iv = sden[m];
    float4 o; o.x=sx*iv; o.y=sy*iv; o.z=sz*iv; o.w=sw2*iv;
    st4(&sM[m][d4], o);
  }
  __syncthreads();
  int i0=(t>>4)*4, j0=(t&15)*4;
  float c[4][4]={};
  mm_tile(c, sW, sM, i0, j0);
  float* P = ws + OFF_P + (size_t)h*4096;
  #pragma unroll
  for(int r=0;r<4;r++){
    float4 o; o.x=c[r][0]; o.y=c[r][1]; o.z=c[r][2]; o.w=c[r][3];
    st4(P + (i0+r)*64 + j0, o);
  }
}

// ---------------- 5. X = rowsoftmax(Q . KL^T) @ P ----------------
// 3 LDS buffers (E overwrites Q staging); row sums via 16-lane shfl reduce (no serial section)
__global__ __launch_bounds__(256) void final_kernel(const float* __restrict__ Qg, float* __restrict__ out, const float* __restrict__ ws){
  __shared__ float sKLT[64][PAD];
  __shared__ float sP[64][PAD];
  __shared__ float sQE[64][PAD];
  int bid=blockIdx.x, t=threadIdx.x;
  int h=bid>>6, s0=(bid&63)*64;
  const float* KL = ws + OFF_KL + (size_t)h*4096;
  const float* P  = ws + OFF_P  + (size_t)h*4096;
  const float* Qb = Qg + ((size_t)h*SEQ + (size_t)s0)*DIM;
  for(int i=t;i<1024;i+=256){
    int m=i>>4, d4=(i&15)*4;
    float4 v = ld4(KL + m*64 + d4);
    sKLT[d4+0][m]=v.x; sKLT[d4+1][m]=v.y; sKLT[d4+2][m]=v.z; sKLT[d4+3][m]=v.w;
    st4(&sP[m][d4], ld4(P + m*64 + d4));
    float4 q = ld4(Qb + (size_t)m*DIM + d4);
    q.x*=INV_SCALE; q.y*=INV_SCALE; q.z*=INV_SCALE; q.w*=INV_SCALE;
    st4(&sQE[m][d4], q);
  }
  __syncthreads();
  int i0=(t>>4)*4, j0=(t&15)*4;
  float l[4][4]={};
  mm_tile(l, sQE, sKLT, i0, j0);
  // exp + per-row sums in registers (threads sharing i0 are 16 consecutive lanes of one wave)
  float e[4][4]; float rs[4];
  #pragma unroll
  for(int r=0;r<4;r++){
    float s=0.f;
    #pragma unroll
    for(int cc=0;cc<4;cc++){ e[r][cc]=__expf(l[r][cc]); s+=e[r][cc]; }
    rs[r]=s;
  }
  #pragma unroll
  for(int r=0;r<4;r++){
    rs[r]+=__shfl_xor(rs[r],1);
    rs[r]+=__shfl_xor(rs[r],2);
    rs[r]+=__shfl_xor(rs[r],4);
    rs[r]+=__shfl_xor(rs[r],8);
  }
  __syncthreads();    // all reads of sQE (as Q) done -> overwrite with E
  #pragma unroll
  for(int r=0;r<4;r++){ float4 o; o.x=e[r][0]; o.y=e[r][1]; o.z=e[r][2]; o.w=e[r][3]; st4(&sQE[i0+r][j0], o); }
  __syncthreads();
  float c[4][4]={};
  mm_tile(c, sQE, sP, i0, j0);
  #pragma unroll
  for(int r=0;r<4;r++){
    float iv = 1.0f/rs[r];
    float4 o; o.x=c[r][0]*iv; o.y=c[r][1]*iv; o.z=c[r][2]*iv; o.w=c[r][3]*iv;
    st4(out + ((size_t)h*SEQ + (size_t)(s0+i0+r))*DIM + j0, o);
  }
}

extern "C" void kernel_launch(void* const* d_in, const int* in_sizes, int n_in,
                              void* d_out, int out_size, void* d_ws, size_t ws_size,
                              hipStream_t stream) {
  const float* Q = (const float*)d_in[0];
  const float* K = (const float*)d_in[1];
  const float* V = (const float*)d_in[2];
  float* out = (float*)d_out;
  float* ws  = (float*)d_ws;

  pool_kernel   <<<BH*32, 256, 0, stream>>>(Q, K, ws);
  k2_kernel     <<<BH,    256, 0, stream>>>(ws);
  fused_kernel  <<<BH + BH*NCHUNK, 256, 0, stream>>>(K, V, ws);
  combine_kernel<<<BH,    256, 0, stream>>>(ws);
  final_kernel  <<<BH*64, 256, 0, stream>>>(Q, out, ws);
}

// Round 2
// 311.366 us; speedup vs baseline: 1.0393x; 1.0393x over previous
//
#include <hip/hip_runtime.h>
#include <cstdint>

#define BH 48
#define SEQ 4096
#define DIM 64
#define SEG 64
#define NCHUNK 8
#define CHUNK 512
#define PAD 68

static constexpr float INV_SCALE = 0.35355339059327379f; // 1/sqrt(sqrt(64))

// workspace float offsets
#define OFF_QL   0u        // 48*4096
#define OFF_KL   196608u   // 48*4096
#define OFF_K2   393216u   // 48*4096
#define OFF_W    589824u   // 48*4096
#define OFF_P    786432u   // 48*4096
#define OFF_MNUM 983040u   // 48*8*4096
#define OFF_MDEN 2555904u  // 48*8*64
#define OFF_CMAX 2580480u  // 48
#define OFF_RMAX 2580528u  // 48  (total 2580576 floats ~ 10.3 MB)

__device__ __forceinline__ float4 ld4(const float* p){ return *reinterpret_cast<const float4*>(p); }
__device__ __forceinline__ void st4(float* p, float4 v){ *reinterpret_cast<float4*>(p) = v; }

// C[4][4] += A[i0..i0+3][:] * B[:][j0..j0+3], 64-deep, LDS operands (pad=68 keeps 16B align)
__device__ __forceinline__ void mm_tile(float c[4][4], const float (*A)[PAD], const float (*B)[PAD], int i0, int j0){
  #pragma unroll 4
  for(int k=0;k<64;k+=4){
    float4 a4[4];
    #pragma unroll
    for(int r=0;r<4;r++) a4[r] = ld4(&A[i0+r][k]);
    #pragma unroll
    for(int kk=0;kk<4;kk++){
      float4 bv = ld4(&B[k+kk][j0]);
      #pragma unroll
      for(int r=0;r<4;r++){
        float a = ((const float*)&a4[r])[kk];
        c[r][0] += a*bv.x; c[r][1] += a*bv.y; c[r][2] += a*bv.z; c[r][3] += a*bv.w;
      }
    }
  }
}

// C[4][4] += A * (dg*I - B)   (Newton-Schulz steps)
__device__ __forceinline__ void mm_tile_diag(float c[4][4], const float (*A)[PAD], const float (*B)[PAD], int i0, int j0, float dg){
  #pragma unroll 4
  for(int k=0;k<64;k+=4){
    float4 a4[4];
    #pragma unroll
    for(int r=0;r<4;r++) a4[r] = ld4(&A[i0+r][k]);
    #pragma unroll
    for(int kk=0;kk<4;kk++){
      float4 bv = ld4(&B[k+kk][j0]);
      float b0=-bv.x, b1=-bv.y, b2=-bv.z, b3=-bv.w;
      int dd = k+kk-j0;
      if(dd==0) b0+=dg; else if(dd==1) b1+=dg; else if(dd==2) b2+=dg; else if(dd==3) b3+=dg;
      #pragma unroll
      for(int r=0;r<4;r++){
        float a = ((const float*)&a4[r])[kk];
        c[r][0]+=a*b0; c[r][1]+=a*b1; c[r][2]+=a*b2; c[r][3]+=a*b3;
      }
    }
  }
}

// ---------------- 1. landmark pooling (reads Q,K once; writes scaled QL,KL) ----------------
__global__ __launch_bounds__(256) void pool_kernel(const float* __restrict__ Qg, const float* __restrict__ Kg, float* __restrict__ ws){
  int bx = blockIdx.x;              // 48 heads * 2 tensors * 16 landmark-groups = 1536
  int head = bx >> 5;
  int rest = bx & 31;
  int tensor = rest >> 4;           // 0:Q 1:K
  int l0 = (rest & 15) * 4;
  int t = threadIdx.x;
  int ll = t >> 6;                  // wave id -> local landmark
  int lane = t & 63;
  int d4 = (lane & 15) * 4;
  int rq = lane >> 4;               // row phase 0..3
  const float* src = tensor ? Kg : Qg;
  float* dst = ws + (tensor ? OFF_KL : OFF_QL);
  int l = l0 + ll;
  const float* base = src + ((size_t)head*SEQ + (size_t)l*SEG)*DIM + d4;
  float sx=0.f, sy=0.f, sz=0.f, sw=0.f;
  #pragma unroll 4
  for(int r=rq; r<SEG; r+=4){
    float4 v = ld4(base + (size_t)r*DIM);
    sx+=v.x; sy+=v.y; sz+=v.z; sw+=v.w;
  }
  sx += __shfl_xor(sx,16); sy += __shfl_xor(sy,16); sz += __shfl_xor(sz,16); sw += __shfl_xor(sw,16);
  sx += __shfl_xor(sx,32); sy += __shfl_xor(sy,32); sz += __shfl_xor(sz,32); sw += __shfl_xor(sw,32);
  if(rq==0){
    const float sc = INV_SCALE / 64.0f;
    float4 o; o.x=sx*sc; o.y=sy*sc; o.z=sz*sc; o.w=sw*sc;
    st4(dst + ((size_t)head*64 + l)*DIM + d4, o);
  }
}

// ---------------- 2. kernel_2 softmax + per-head L1 row/col max ----------------
__global__ __launch_bounds__(256) void k2_kernel(float* __restrict__ ws){
  __shared__ float sQ[64][65];
  __shared__ float sK[64][65];
  __shared__ float sE[64][65];
  __shared__ float red[128];
  int h = blockIdx.x, t = threadIdx.x;
  const float* QL = ws + OFF_QL + (size_t)h*4096;
  const float* KL = ws + OFF_KL + (size_t)h*4096;
  for(int i=t;i<4096;i+=256){ sQ[i>>6][i&63]=QL[i]; sK[i>>6][i&63]=KL[i]; }
  __syncthreads();
  int i = t>>2, q = t&3;
  float l[16];
  #pragma unroll
  for(int jj=0;jj<16;jj++){
    int j = q*16+jj;
    float s=0.f;
    for(int d=0;d<64;d++) s += sQ[i][d]*sK[j][d];
    l[jj]=s;
  }
  float mx = l[0];
  #pragma unroll
  for(int jj=1;jj<16;jj++) mx = fmaxf(mx,l[jj]);
  mx = fmaxf(mx, __shfl_xor(mx,1));
  mx = fmaxf(mx, __shfl_xor(mx,2));
  float sum=0.f;
  #pragma unroll
  for(int jj=0;jj<16;jj++){ l[jj]=__expf(l[jj]-mx); sum+=l[jj]; }
  sum += __shfl_xor(sum,1);
  sum += __shfl_xor(sum,2);
  float inv = 1.0f/sum;
  #pragma unroll
  for(int jj=0;jj<16;jj++) sE[i][q*16+jj] = l[jj]*inv;
  __syncthreads();
  float* K2 = ws + OFF_K2 + (size_t)h*4096;
  for(int idx=t; idx<4096; idx+=256) K2[idx] = sE[idx>>6][idx&63];
  if(t<64){
    float cs=0.f, rs=0.f;
    for(int r=0;r<64;r++){ cs += sE[r][t]; rs += sE[t][r]; }
    red[t]=cs; red[64+t]=rs;
  }
  __syncthreads();
  if(t==0){
    float cm=0.f, rm=0.f;
    for(int j=0;j<64;j++){ cm=fmaxf(cm,red[j]); rm=fmaxf(rm,red[64+j]); }
    ws[OFF_CMAX+h]=cm; ws[OFF_RMAX+h]=rm;
  }
}

// ---------------- 3. fused: Newton-Schulz (blocks 0..47) || kernel_3@V partials (blocks 48..431) ----------------
// chunk path: register double-buffer prefetch of K/V tiles (hide HBM latency under the matmuls)
__global__ __launch_bounds__(256) void fused_kernel(const float* __restrict__ Kg, const float* __restrict__ Vg, float* __restrict__ ws){
  __shared__ float buf[4][64][PAD];
  __shared__ float sscale;
  int bid = blockIdx.x, t = threadIdx.x;
  int i0 = (t>>4)*4, j0 = (t&15)*4;
  if(bid < BH){
    // ---- Newton-Schulz pseudo-inverse of kernel_2, head=bid ----
    int h = bid;
    float (*Km)[PAD]=buf[0]; float (*Vm)[PAD]=buf[1]; float (*B1)[PAD]=buf[2]; float (*B2)[PAD]=buf[3];
    const float* K2 = ws + OFF_K2 + (size_t)h*4096;
    for(int i=t;i<4096;i+=256) Km[i>>6][i&63]=K2[i];
    if(t==0){
      float cm=0.f, rm=0.f;
      for(int j=0;j<BH;j++){ cm=fmaxf(cm,ws[OFF_CMAX+j]); rm=fmaxf(rm,ws[OFF_RMAX+j]); }
      sscale = 1.0f/(cm*rm);   // global (all heads) scale, matches reference
    }
    __syncthreads();
    float scale = sscale;
    for(int i=t;i<4096;i+=256) Vm[i>>6][i&63] = scale * Km[i&63][i>>6];  // scale * Km^T
    __syncthreads();
    for(int it=0; it<6; it++){
      { // B1 = Km @ Vm   (KV)
        float c[4][4]={};
        mm_tile(c,Km,Vm,i0,j0);
        #pragma unroll
        for(int r=0;r<4;r++){ float4 o; o.x=c[r][0];o.y=c[r][1];o.z=c[r][2];o.w=c[r][3]; st4(&B1[i0+r][j0],o); }
        __syncthreads();
      }
      { // B2 = KV @ (7I - KV)
        float c[4][4]={};
        mm_tile_diag(c,B1,B1,i0,j0,7.0f);
        #pragma unroll
        for(int r=0;r<4;r++){ float4 o; o.x=c[r][0];o.y=c[r][1];o.z=c[r][2];o.w=c[r][3]; st4(&B2[i0+r][j0],o); }
        __syncthreads();
      }
      { // B1 = KV @ (15I - B2)   (in-place on B1: compute -> barrier -> write)
        float c[4][4]={};
        mm_tile_diag(c,B1,B2,i0,j0,15.0f);
        __syncthreads();
        #pragma unroll
        for(int r=0;r<4;r++){ float4 o; o.x=c[r][0];o.y=c[r][1];o.z=c[r][2];o.w=c[r][3]; st4(&B1[i0+r][j0],o); }
        __syncthreads();
      }
      { // Vm = 0.25 * Vm @ (13I - B1)
        float c[4][4]={};
        mm_tile_diag(c,Vm,B1,i0,j0,13.0f);
        __syncthreads();
        #pragma unroll
        for(int r=0;r<4;r++){ float4 o; o.x=0.25f*c[r][0];o.y=0.25f*c[r][1];o.z=0.25f*c[r][2];o.w=0.25f*c[r][3]; st4(&Vm[i0+r][j0],o); }
        __syncthreads();
      }
    }
    float* W = ws + OFF_W + (size_t)h*4096;
    for(int i=t;i<4096;i+=256) W[i] = Vm[i>>6][i&63];
  } else {
    // ---- kernel_3 @ V partial: block = (head, 512-key chunk) ----
    int b = bid - BH;
    int h = b >> 3, ch = b & 7;
    float (*QLT)[PAD]=buf[0]; float (*Kt)[PAD]=buf[1]; float (*Vt)[PAD]=buf[2]; float (*ET)[PAD]=buf[3];
    const float* QL = ws + OFF_QL + (size_t)h*4096;
    for(int i=t;i<1024;i+=256){
      int m=i>>4, d4=(i&15)*4;
      float4 v = ld4(QL + m*64 + d4);
      QLT[d4+0][m]=v.x; QLT[d4+1][m]=v.y; QLT[d4+2][m]=v.z; QLT[d4+3][m]=v.w;   // QL^T for logits
    }
    float acc[4][4]={};
    float den=0.f;
    int mden=t>>2, qden=t&3;
    const int rr = t>>4, dd4 = (t&15)*4;          // this thread's 4 staging rows: rr+16*it
    const size_t kbase = ((size_t)h*SEQ + (size_t)ch*CHUNK)*DIM;
    // prologue: prefetch tile 0 into registers
    float4 kr[4], vr[4];
    #pragma unroll
    for(int it2=0; it2<4; it2++){
      size_t off = kbase + (size_t)(rr + 16*it2)*DIM + dd4;
      kr[it2] = ld4(Kg+off); vr[it2] = ld4(Vg+off);
    }
    for(int tile=0;tile<8;tile++){
      __syncthreads();   // prev tile's LDS reads done (also covers QLT staging on first pass)
      // regs -> LDS
      #pragma unroll
      for(int it2=0; it2<4; it2++){
        int r = rr + 16*it2;
        float4 kv = kr[it2];
        kv.x*=INV_SCALE; kv.y*=INV_SCALE; kv.z*=INV_SCALE; kv.w*=INV_SCALE;
        st4(&Kt[r][dd4], kv);
        st4(&Vt[r][dd4], vr[it2]);
      }
      // issue next tile's global loads (latency hidden under the two matmuls below)
      if(tile<7){
        #pragma unroll
        for(int it2=0; it2<4; it2++){
          size_t off = kbase + (size_t)((tile+1)*64 + rr + 16*it2)*DIM + dd4;
          kr[it2] = ld4(Kg+off); vr[it2] = ld4(Vg+off);
        }
      }
      __syncthreads();
      // logits L[s'][m] = Kt(scaled) . QL
      float l[4][4]={};
      mm_tile(l, Kt, QLT, i0, j0);
      // ET[m][s'] = exp(L[s'][m]) — register 4x4 transpose, float4 stores (separate buffer: no extra barrier)
      #pragma unroll
      for(int cc=0;cc<4;cc++){
        float4 o; o.x=__expf(l[0][cc]); o.y=__expf(l[1][cc]); o.z=__expf(l[2][cc]); o.w=__expf(l[3][cc]);
        st4(&ET[j0+cc][i0], o);
      }
      __syncthreads();
      // denominator partials (softmax over full S; logits tiny so no max-sub needed)
      #pragma unroll
      for(int u=0;u<4;u++){
        float4 e2 = ld4(&ET[mden][qden*16 + u*4]);
        den += e2.x+e2.y+e2.z+e2.w;
      }
      // acc[m][d] += ET[m][s'] * V[s'][d]
      mm_tile(acc, ET, Vt, i0, j0);
    }
    float* num = ws + OFF_MNUM + (size_t)b*4096;
    #pragma unroll
    for(int r=0;r<4;r++){
      float4 o; o.x=acc[r][0]; o.y=acc[r][1]; o.z=acc[r][2]; o.w=acc[r][3];
      st4(num + (i0+r)*64 + j0, o);
    }
    den += __shfl_xor(den,1);
    den += __shfl_xor(den,2);
    if(qden==0) ws[OFF_MDEN + (size_t)b*64 + mden] = den;
  }
}

// ---------------- 4. combine partials -> M, then P = W @ M ----------------
__global__ __launch_bounds__(256) void combine_kernel(float* __restrict__ ws){
  __shared__ float sW[64][PAD];
  __shared__ float sM[64][PAD];
  __shared__ float sden[64];
  int h=blockIdx.x, t=threadIdx.x;
  if(t<64){
    float s=0.f;
    for(int c=0;c<NCHUNK;c++) s += ws[OFF_MDEN + ((size_t)h*NCHUNK+c)*64 + t];
    sden[t]=1.0f/s;
  }
  for(int i=t;i<4096;i+=256) sW[i>>6][i&63] = ws[OFF_W + (size_t)h*4096 + i];
  __syncthreads();
  for(int i=t;i<1024;i+=256){
    int m=i>>4, d4=(i&15)*4;
    float sx=0.f,sy=0.f,sz=0.f,sw2=0.f;
    for(int c=0;c<NCHUNK;c++){
      float4 v = ld4(ws + OFF_MNUM + ((size_t)h*NCHUNK+c)*4096 + m*64 + d4);
      sx+=v.x; sy+=v.y; sz+=v.z; sw2+=v.w;
    }
    float iv = sden[m];
    float4 o; o.x=sx*iv; o.y=sy*iv; o.z=sz*iv; o.w=sw2*iv;
    st4(&sM[m][d4], o);
  }
  __syncthreads();
  int i0=(t>>4)*4, j0=(t&15)*4;
  float c[4][4]={};
  mm_tile(c, sW, sM, i0, j0);
  float* P = ws + OFF_P + (size_t)h*4096;
  #pragma unroll
  for(int r=0;r<4;r++){
    float4 o; o.x=c[r][0]; o.y=c[r][1]; o.z=c[r][2]; o.w=c[r][3];
    st4(P + (i0+r)*64 + j0, o);
  }
}

// ---------------- 5. X = rowsoftmax(Q . KL^T) @ P ----------------
// 3 LDS buffers (E overwrites Q staging); row sums via 16-lane shfl reduce (no serial section)
__global__ __launch_bounds__(256) void final_kernel(const float* __restrict__ Qg, float* __restrict__ out, const float* __restrict__ ws){
  __shared__ float sKLT[64][PAD];
  __shared__ float sP[64][PAD];
  __shared__ float sQE[64][PAD];
  int bid=blockIdx.x, t=threadIdx.x;
  int h=bid>>6, s0=(bid&63)*64;
  const float* KL = ws + OFF_KL + (size_t)h*4096;
  const float* P  = ws + OFF_P  + (size_t)h*4096;
  const float* Qb = Qg + ((size_t)h*SEQ + (size_t)s0)*DIM;
  for(int i=t;i<1024;i+=256){
    int m=i>>4, d4=(i&15)*4;
    float4 v = ld4(KL + m*64 + d4);
    sKLT[d4+0][m]=v.x; sKLT[d4+1][m]=v.y; sKLT[d4+2][m]=v.z; sKLT[d4+3][m]=v.w;
    st4(&sP[m][d4], ld4(P + m*64 + d4));
    float4 q = ld4(Qb + (size_t)m*DIM + d4);
    q.x*=INV_SCALE; q.y*=INV_SCALE; q.z*=INV_SCALE; q.w*=INV_SCALE;
    st4(&sQE[m][d4], q);
  }
  __syncthreads();
  int i0=(t>>4)*4, j0=(t&15)*4;
  float l[4][4]={};
  mm_tile(l, sQE, sKLT, i0, j0);
  // exp + per-row sums in registers (threads sharing i0 are 16 consecutive lanes of one wave)
  float e[4][4]; float rs[4];
  #pragma unroll
  for(int r=0;r<4;r++){
    float s=0.f;
    #pragma unroll
    for(int cc=0;cc<4;cc++){ e[r][cc]=__expf(l[r][cc]); s+=e[r][cc]; }
    rs[r]=s;
  }
  #pragma unroll
  for(int r=0;r<4;r++){
    rs[r]+=__shfl_xor(rs[r],1);
    rs[r]+=__shfl_xor(rs[r],2);
    rs[r]+=__shfl_xor(rs[r],4);
    rs[r]+=__shfl_xor(rs[r],8);
  }
  __syncthreads();    // all reads of sQE (as Q) done -> overwrite with E
  #pragma unroll
  for(int r=0;r<4;r++){ float4 o; o.x=e[r][0]; o.y=e[r][1]; o.z=e[r][2]; o.w=e[r][3]; st4(&sQE[i0+r][j0], o); }
  __syncthreads();
  float c[4][4]={};
  mm_tile(c, sQE, sP, i0, j0);
  #pragma unroll
  for(int r=0;r<4;r++){
    float iv = 1.0f/rs[r];
    float4 o; o.x=c[r][0]*iv; o.y=c[r][1]*iv; o.z=c[r][2]*iv; o.w=c[r][3]*iv;
    st4(out + ((size_t)h*SEQ + (size_t)(s0+i0+r))*DIM + j0, o);
  }
}

extern "C" void kernel_launch(void* const* d_in, const int* in_sizes, int n_in,
                              void* d_out, int out_size, void* d_ws, size_t ws_size,
                              hipStream_t stream) {
  const float* Q = (const float*)d_in[0];
  const float* K = (const float*)d_in[1];
  const float* V = (const float*)d_in[2];
  float* out = (float*)d_out;
  float* ws  = (float*)d_ws;

  pool_kernel   <<<BH*32, 256, 0, stream>>>(Q, K, ws);
  k2_kernel     <<<BH,    256, 0, stream>>>(ws);
  fused_kernel  <<<BH + BH*NCHUNK, 256, 0, stream>>>(K, V, ws);
  combine_kernel<<<BH,    256, 0, stream>>>(ws);
  final_kernel  <<<BH*64, 256, 0, stream>>>(Q, out, ws);
}